// Round 4
// baseline (3771.240 us; speedup 1.0000x reference)
//
#include <hip/hip_runtime.h>

#define NB 8
#define NC 64
#define NN 4096
#define NO 64
#define KK 20
#define EPSV 1e-5f
#define SLOPE 0.2f
#define CAP 72

// ws layout (float units):
// y1 : [B][N][O]   off 0         (2097152)
// y2 : [B][N][O]   off 2097152
// xx : [B][N]      off 4194304   (32768)
// idx: [B][N][K]   off 4227072   (655360 ints)
// wa : [C][O]      off 4882432   (4096)
// wb : [C][O]      off 4886528   (4096)

__global__ void k0_wprep(const float* __restrict__ W,
                         float* __restrict__ wa, float* __restrict__ wb) {
  int t = threadIdx.x;
  for (int i = t; i < NC * NO; i += 256) {
    int o = i & 63, c = i >> 6;
    float w1 = W[o * 128 + c];
    float w2 = W[o * 128 + 64 + c];
    wa[i] = w1 - w2;  // [c][o]
    wb[i] = w2;
  }
}

__global__ __launch_bounds__(256) void k1_feat(const float* __restrict__ x,
    const float* __restrict__ waT, const float* __restrict__ wbT,
    float* __restrict__ y1, float* __restrict__ y2, float* __restrict__ xxg) {
  __shared__ __align__(16) float xs[NC * 64];   // [c][n]
  __shared__ __align__(16) float wa[NC * NO];   // [c][o]
  __shared__ __align__(16) float wb[NC * NO];
  int t = threadIdx.x;
  int b = blockIdx.x >> 6;
  int gr0 = (blockIdx.x & 63) << 6;
  const float* xb = x + (size_t)b * NC * NN;
  #pragma unroll
  for (int k = 0; k < 4; ++k) {
    int i4 = t + k * 256;            // 0..1023
    int c = i4 >> 4, col4 = (i4 & 15) << 2;
    *(float4*)&xs[c * 64 + col4] = *(const float4*)&xb[(size_t)c * NN + gr0 + col4];
    *(float4*)&wa[c * 64 + col4] = *(const float4*)&waT[c * 64 + col4];
    *(float4*)&wb[c * 64 + col4] = *(const float4*)&wbT[c * 64 + col4];
  }
  __syncthreads();
  if (t < 64) {
    float s = 0.f;
    #pragma unroll
    for (int c = 0; c < NC; ++c) { float v = xs[c * 64 + t]; s = fmaf(v, v, s); }
    xxg[b * NN + gr0 + t] = s;
  }
  int o = t & 63, w = t >> 6;
  for (int j = 0; j < 16; ++j) {
    int n = j * 4 + w;
    float a1 = 0.f, a2 = 0.f;
    #pragma unroll
    for (int c = 0; c < NC; ++c) {
      float xv = xs[c * 64 + n];               // wave-uniform broadcast
      a1 = fmaf(wa[c * 64 + o], xv, a1);
      a2 = fmaf(wb[c * 64 + o], xv, a2);
    }
    size_t base = ((size_t)b * NN + gr0 + n) * NO + o;
    y1[base] = a1;
    y2[base] = a2;
  }
}

// exact top-20 of row r's candidate list; if fin, write out; else rewrite list+cut
__device__ __forceinline__ void compact_row(float* keyL, unsigned short* idxL,
    unsigned* cnt, float* cutk, int* cuti, int r, bool fin, int* outp) {
  int c = (int)cnt[r]; if (c > CAP) c = CAP;
  float kv[KK]; int ki[KK];
  #pragma unroll
  for (int j = 0; j < KK; ++j) { kv[j] = 3.4e38f; ki[j] = 0x7FFFFFFF; }
  for (int s = 0; s < c; ++s) {
    float k = keyL[r * CAP + s];
    int m = (int)idxL[r * CAP + s];
    bool ins = (k < kv[KK - 1]) || (k == kv[KK - 1] && m < ki[KK - 1]);
    if (ins) {
      #pragma unroll
      for (int j = KK - 1; j >= 1; --j) {
        bool sh = (k < kv[j - 1]) || (k == kv[j - 1] && m < ki[j - 1]);
        bool he = (k < kv[j]) || (k == kv[j] && m < ki[j]);
        float pv = kv[j - 1]; int pi = ki[j - 1];
        kv[j] = sh ? pv : (he ? k : kv[j]);
        ki[j] = sh ? pi : (he ? m : ki[j]);
      }
      if ((k < kv[0]) || (k == kv[0] && m < ki[0])) { kv[0] = k; ki[0] = m; }
    }
  }
  if (fin) {
    #pragma unroll
    for (int j = 0; j < KK; ++j) outp[j] = ki[j];
  } else {
    #pragma unroll
    for (int j = 0; j < KK; ++j) {
      keyL[r * CAP + j] = kv[j];
      idxL[r * CAP + j] = (unsigned short)ki[j];
    }
    cnt[r] = KK;
    cutk[r] = kv[KK - 1];
    cuti[r] = ki[KK - 1];
  }
}

// ----- fused Gram + per-row exact top-K, single pass, incremental cut -----
__global__ __launch_bounds__(256, 2) void k2_topk(const float* __restrict__ x,
    const float* __restrict__ xxg, int* __restrict__ idxg) {
  __shared__ __align__(16) float As[64 * 64];    // [c][r] 16KB
  __shared__ __align__(16) float Bs[64 * 128];   // [c][m] 32KB
  __shared__ __align__(16) float xxs[128];
  __shared__ float xxrs[64];
  __shared__ float cutk[64];
  __shared__ int cuti[64];
  __shared__ unsigned cnt[64];
  __shared__ float keyL[64 * CAP];               // 18KB
  __shared__ unsigned short idxL[64 * CAP];      // 9KB
  __shared__ int pendf;

  int t = threadIdx.x;
  int b = blockIdx.x >> 6;
  int gr0 = (blockIdx.x & 63) << 6;
  const float* xb = x + (size_t)b * NC * NN;
  int ty = t >> 4, tx = t & 15;  // rows ty*4.., cols tx*8..

  #pragma unroll
  for (int k = 0; k < 4; ++k) {
    int i4 = t + k * 256;
    int c = i4 >> 4, col4 = (i4 & 15) << 2;
    *(float4*)&As[c * 64 + col4] = *(const float4*)&xb[(size_t)c * NN + gr0 + col4];
  }
  if (t < 64) {
    xxrs[t] = xxg[b * NN + gr0 + t];
    cutk[t] = 3.4e38f;
    cuti[t] = 0x7FFFFFFF;
    cnt[t] = 0;
  }
  __syncthreads();

  float xr[4];
  #pragma unroll
  for (int i = 0; i < 4; ++i) xr[i] = xxrs[ty * 4 + i];

  for (int mt = 0; mt < 32; ++mt) {
    int gm0 = mt << 7;
    __syncthreads();  // protect Bs restage
    #pragma unroll
    for (int k = 0; k < 8; ++k) {
      int i4 = t + k * 256;
      int c = i4 >> 5, col4 = (i4 & 31) << 2;
      *(float4*)&Bs[c * 128 + col4] = *(const float4*)&xb[(size_t)c * NN + gm0 + col4];
    }
    if (t < 32) *(float4*)&xxs[t * 4] = *(const float4*)&xxg[b * NN + gm0 + t * 4];
    __syncthreads();

    float acc[4][8];
    #pragma unroll
    for (int i = 0; i < 4; ++i)
      #pragma unroll
      for (int j = 0; j < 8; ++j) acc[i][j] = 0.f;

    #pragma unroll 4
    for (int c = 0; c < 64; ++c) {
      float4 av = *(const float4*)&As[c * 64 + ty * 4];
      float4 b0 = *(const float4*)&Bs[c * 128 + tx * 8];
      float4 b1 = *(const float4*)&Bs[c * 128 + tx * 8 + 4];
      float a_[4] = {av.x, av.y, av.z, av.w};
      float b_[8] = {b0.x, b0.y, b0.z, b0.w, b1.x, b1.y, b1.z, b1.w};
      #pragma unroll
      for (int i = 0; i < 4; ++i)
        #pragma unroll
        for (int j = 0; j < 8; ++j)
          acc[i][j] = fmaf(a_[i], b_[j], acc[i][j]);
    }

    // keys in-place: key = xx[m] - 2*G  (row-const xx[r] dropped; ordering same)
    float xm[8];
    #pragma unroll
    for (int j = 0; j < 8; ++j) xm[j] = xxs[tx * 8 + j];
    #pragma unroll
    for (int i = 0; i < 4; ++i)
      #pragma unroll
      for (int j = 0; j < 8; ++j)
        acc[i][j] = fmaf(-2.f, acc[i][j], xm[j]);

    // append-with-retry: keys stay in regs until stored or provably dominated
    unsigned pending = 0xFFFFFFFFu;
    for (;;) {
      float ck[4]; int ci[4];
      #pragma unroll
      for (int i = 0; i < 4; ++i) { ck[i] = cutk[ty * 4 + i]; ci[i] = cuti[ty * 4 + i]; }
      #pragma unroll
      for (int i = 0; i < 4; ++i) {
        int r = ty * 4 + i;
        #pragma unroll
        for (int j = 0; j < 8; ++j) {
          unsigned bit = 1u << (i * 8 + j);
          if (pending & bit) {
            float k = acc[i][j];
            int m = gm0 + tx * 8 + j;
            if ((k < ck[i]) || (k == ck[i] && m < ci[i])) {
              unsigned slot = atomicAdd(&cnt[r], 1u);
              if (slot < CAP) {
                keyL[r * CAP + slot] = k;
                idxL[r * CAP + slot] = (unsigned short)m;
                pending &= ~bit;
              }
              // else keep pending: row overflowed, will compact+retry
            } else {
              pending &= ~bit;  // dominated by >=20 seen keys
            }
          }
        }
      }
      __syncthreads();
      if (t == 0) pendf = 0;
      __syncthreads();
      if (pending) pendf = 1;  // benign race: all write 1
      __syncthreads();
      if (!pendf) break;
      if (t < 64 && cnt[t] > CAP)
        compact_row(keyL, idxL, cnt, cutk, cuti, t, false, nullptr);
      __syncthreads();
    }
  }

  // final exact top-20 per row (lists hold a superset of the true top-20)
  __syncthreads();
  if (t < 64) {
    int* op = idxg + ((size_t)b * NN + gr0 + t) * KK;
    compact_row(keyL, idxL, cnt, cutk, cuti, t, true, op);
  }
}

__global__ __launch_bounds__(256) void k3_out(const float* __restrict__ y1,
    const float* __restrict__ y2, const int* __restrict__ idxg,
    const float* __restrict__ gamma, const float* __restrict__ beta,
    const float* __restrict__ rmean, const float* __restrict__ rvar,
    float* __restrict__ out) {
  __shared__ int sidx[64 * KK];
  __shared__ float ot[64 * 65];  // [o][n], pad 65
  int t = threadIdx.x;
  int b = blockIdx.x >> 6;
  int gr0 = (blockIdx.x & 63) << 6;
  const int* ib = idxg + ((size_t)b * NN + gr0) * KK;
  for (int i = t; i < 64 * KK; i += 256) sidx[i] = ib[i];
  int l = t & 63, w = t >> 6;
  float sc = gamma[l] * rsqrtf(rvar[l] + EPSV);
  float tt = fmaf(-rmean[l], sc, beta[l]);
  __syncthreads();
  const float* y2b = y2 + (size_t)b * NN * NO;
  for (int rr = 0; rr < 16; ++rr) {
    int row = w * 16 + rr;
    float v1 = y1[((size_t)b * NN + gr0 + row) * NO + l];
    float best = -3.4e38f;
    #pragma unroll 4
    for (int k = 0; k < KK; ++k) {
      int m = sidx[row * KK + k];                 // wave-uniform broadcast
      float v = v1 + y2b[(size_t)m * NO + l];     // coalesced 256B gather
      v = fmaf(v, sc, tt);
      v = v >= 0.f ? v : SLOPE * v;
      best = fmaxf(best, v);
    }
    ot[l * 65 + row] = best;
  }
  __syncthreads();
  float* ob = out + (size_t)b * NO * NN;
  for (int i = t; i < 4096; i += 256) {
    int o = i >> 6, n = i & 63;
    ob[(size_t)o * NN + gr0 + n] = ot[o * 65 + n];  // coalesced
  }
}

extern "C" void kernel_launch(void* const* d_in, const int* in_sizes, int n_in,
                              void* d_out, int out_size, void* d_ws, size_t ws_size,
                              hipStream_t stream) {
  const float* x     = (const float*)d_in[0];
  const float* W     = (const float*)d_in[1];
  const float* gamma = (const float*)d_in[2];
  const float* beta  = (const float*)d_in[3];
  const float* rmean = (const float*)d_in[4];
  const float* rvar  = (const float*)d_in[5];
  float* ws  = (float*)d_ws;
  float* y1  = ws;
  float* y2  = ws + 2097152;
  float* xx  = ws + 4194304;
  int*   idx = (int*)(ws + 4227072);
  float* wa  = ws + 4882432;
  float* wb  = ws + 4886528;
  float* out = (float*)d_out;

  hipLaunchKernelGGL(k0_wprep, dim3(1),   dim3(256), 0, stream, W, wa, wb);
  hipLaunchKernelGGL(k1_feat,  dim3(512), dim3(256), 0, stream, x, wa, wb, y1, y2, xx);
  hipLaunchKernelGGL(k2_topk,  dim3(512), dim3(256), 0, stream, x, xx, idx);
  hipLaunchKernelGGL(k3_out,   dim3(512), dim3(256), 0, stream, y1, y2, idx,
                     gamma, beta, rmean, rvar, out);
}

// Round 5
// 683.321 us; speedup vs baseline: 5.5190x; 5.5190x over previous
//
#include <hip/hip_runtime.h>

#define NB 8
#define NC 64
#define NN 4096
#define NO 64
#define KK 20
#define EPSV 1e-5f
#define SLOPE 0.2f

// ws layout (float words):
// y1   : [B][N][O]          @0         2097152
// y2   : [B][N][O]          @2097152   2097152
// xx   : [B][N]             @4194304   32768
// keys2: [B][N][2][20] f32  @4227072   1310720
// idx2 : [B][N][2][20] u16  @5537792   655360 words
// wa   : [C][O]             @6193152   4096
// wb   : [C][O]             @6197248   4096
// total 6201344 words = 24.8 MB

__global__ void k0_wprep(const float* __restrict__ W,
                         float* __restrict__ wa, float* __restrict__ wb) {
  int t = threadIdx.x;
  for (int i = t; i < NC * NO; i += 256) {
    int o = i & 63, c = i >> 6;
    float w1 = W[o * 128 + c];
    float w2 = W[o * 128 + 64 + c];
    wa[i] = w1 - w2;  // [c][o]
    wb[i] = w2;
  }
}

__global__ __launch_bounds__(256) void k1_feat(const float* __restrict__ x,
    const float* __restrict__ waT, const float* __restrict__ wbT,
    float* __restrict__ y1, float* __restrict__ y2, float* __restrict__ xxg) {
  __shared__ __align__(16) float xs[NC * 64];   // [c][n]
  __shared__ __align__(16) float wa[NC * NO];   // [c][o]
  __shared__ __align__(16) float wb[NC * NO];
  int t = threadIdx.x;
  int b = blockIdx.x >> 6;
  int gr0 = (blockIdx.x & 63) << 6;
  const float* xb = x + (size_t)b * NC * NN;
  #pragma unroll
  for (int k = 0; k < 4; ++k) {
    int i4 = t + k * 256;
    int c = i4 >> 4, col4 = (i4 & 15) << 2;
    *(float4*)&xs[c * 64 + col4] = *(const float4*)&xb[(size_t)c * NN + gr0 + col4];
    *(float4*)&wa[c * 64 + col4] = *(const float4*)&waT[c * 64 + col4];
    *(float4*)&wb[c * 64 + col4] = *(const float4*)&wbT[c * 64 + col4];
  }
  __syncthreads();
  if (t < 64) {
    float s = 0.f;
    #pragma unroll
    for (int c = 0; c < NC; ++c) { float v = xs[c * 64 + t]; s = fmaf(v, v, s); }
    xxg[b * NN + gr0 + t] = s;
  }
  int o = t & 63, w = t >> 6;
  for (int j = 0; j < 16; ++j) {
    int n = j * 4 + w;
    float a1 = 0.f, a2 = 0.f;
    #pragma unroll
    for (int c = 0; c < NC; ++c) {
      float xv = xs[c * 64 + n];               // wave-uniform broadcast
      a1 = fmaf(wa[c * 64 + o], xv, a1);
      a2 = fmaf(wb[c * 64 + o], xv, a2);
    }
    size_t base = ((size_t)b * NN + gr0 + n) * NO + o;
    y1[base] = a1;
    y2[base] = a2;
  }
}

// ----- fused Gram + per-row exact top-K (column half), shared-cut pruned -----
// grid 1024: blk = b*128 + rowgroup*2 + half
__global__ __launch_bounds__(256) void k2_topk(const float* __restrict__ x,
    const float* __restrict__ xxg, float* __restrict__ keys2,
    unsigned short* __restrict__ idx2) {
  __shared__ __align__(16) float As[64 * 64];    // [c][r] 16KB; final: mi u16[64][81]
  __shared__ __align__(16) float Bs[64 * 128];   // [c][m] 32KB; per-tile reused as cand[r][m]; final: mv[64][81]
  __shared__ __align__(16) float xxs[128];
  __shared__ __align__(16) float xxr[64];
  __shared__ __align__(16) float cutq[64 * 4];   // [r][q] current private 20th per quarter

  int t = threadIdx.x;
  int blk = blockIdx.x;
  int b = blk >> 7;
  int rem = blk & 127;
  int rg = rem >> 1, half = rem & 1;
  int gr0 = rg << 6;
  int gc0 = half << 11;                          // 0 or 2048
  const float* xb = x + (size_t)b * NC * NN;
  int ty = t >> 4, tx = t & 15;                  // rows ty*4..+3, cols tx*8..+7
  int orow = t & 63, oq = t >> 6;                // scan owner (row, quarter)

  #pragma unroll
  for (int k = 0; k < 4; ++k) {
    int i4 = t + k * 256;
    int c = i4 >> 4, col4 = (i4 & 15) << 2;
    *(float4*)&As[c * 64 + col4] = *(const float4*)&xb[(size_t)c * NN + gr0 + col4];
  }
  if (t < 16) *(float4*)&xxr[t * 4] = *(const float4*)&xxg[b * NN + gr0 + t * 4];
  if (t < 64) {
    float4 inf4 = {3.4e38f, 3.4e38f, 3.4e38f, 3.4e38f};
    *(float4*)&cutq[t * 4] = inf4;
  }
  __syncthreads();

  float xr[4];
  #pragma unroll
  for (int i = 0; i < 4; ++i) xr[i] = xxr[ty * 4 + i];
  (void)xr;  // row-constant dropped from keys; kept for clarity

  float kv[KK]; int ki[KK];
  #pragma unroll
  for (int j = 0; j < KK; ++j) { kv[j] = 3.4e38f; ki[j] = 0; }

  int rotw = (ty & 7) << 2;              // writer swizzle: rot(r)=4*((r>>2)&7), r>>2==ty
  int rotr = ((orow >> 2) & 7) << 2;     // reader swizzle for row orow

  for (int mt = 0; mt < 16; ++mt) {
    int gm0 = gc0 + (mt << 7);
    __syncthreads();  // (a) prev cand reads / cutq writes done before Bs restage
    #pragma unroll
    for (int k = 0; k < 8; ++k) {
      int i4 = t + k * 256;
      int c = i4 >> 5, col4 = (i4 & 31) << 2;
      *(float4*)&Bs[c * 128 + col4] = *(const float4*)&xb[(size_t)c * NN + gm0 + col4];
    }
    if (t < 32) *(float4*)&xxs[t * 4] = *(const float4*)&xxg[b * NN + gm0 + t * 4];
    __syncthreads();  // (b) Bs ready

    float acc[4][8];
    #pragma unroll
    for (int i = 0; i < 4; ++i)
      #pragma unroll
      for (int j = 0; j < 8; ++j) acc[i][j] = 0.f;

    #pragma unroll 4
    for (int c = 0; c < 64; ++c) {
      float4 av = *(const float4*)&As[c * 64 + ty * 4];
      float4 b0 = *(const float4*)&Bs[c * 128 + tx * 8];
      float4 b1 = *(const float4*)&Bs[c * 128 + tx * 8 + 4];
      float a_[4] = {av.x, av.y, av.z, av.w};
      float b_[8] = {b0.x, b0.y, b0.z, b0.w, b1.x, b1.y, b1.z, b1.w};
      #pragma unroll
      for (int i = 0; i < 4; ++i)
        #pragma unroll
        for (int j = 0; j < 8; ++j)
          acc[i][j] = fmaf(a_[i], b_[j], acc[i][j]);
    }

    // keys in regs: key = xx[m] - 2*G (row-constant dropped; ordering identical)
    float xm[8];
    #pragma unroll
    for (int j = 0; j < 8; ++j) xm[j] = xxs[tx * 8 + j];
    #pragma unroll
    for (int i = 0; i < 4; ++i)
      #pragma unroll
      for (int j = 0; j < 8; ++j)
        acc[i][j] = fmaf(-2.f, acc[i][j], xm[j]);

    __syncthreads();  // (c) all Bs reads done -> safe to overwrite Bs as cand

    // cand[r][m] with 32-block rotation swizzle (8-way max both sides)
    #pragma unroll
    for (int i = 0; i < 4; ++i) {
      int r = ty * 4 + i;
      #pragma unroll
      for (int h = 0; h < 2; ++h) {
        int mbw = tx * 8 + h * 4;
        int pos = (mbw & 96) | ((mbw + rotw) & 31);
        float4 v4 = {acc[i][h * 4 + 0], acc[i][h * 4 + 1],
                     acc[i][h * 4 + 2], acc[i][h * 4 + 3]};
        *(float4*)&Bs[r * 128 + pos] = v4;
      }
    }
    __syncthreads();  // (d) cand ready

    // owner scan: shared-cut pruned private exact top-20
    float4 cq = *(const float4*)&cutq[orow * 4];
    float rcut = fminf(fminf(cq.x, cq.y), fminf(cq.z, cq.w));
    #pragma unroll 1
    for (int g = 0; g < 8; ++g) {
      int mb = oq * 32 + g * 4;
      int pos = (mb & 96) | ((mb + rotr) & 31);
      float4 kq = *(const float4*)&Bs[orow * 128 + pos];
      float ke[4] = {kq.x, kq.y, kq.z, kq.w};
      #pragma unroll
      for (int e = 0; e < 4; ++e) {
        float v = ke[e];
        if (v <= rcut && v < kv[KK - 1]) {
          int m = gm0 + mb + e;
          #pragma unroll
          for (int j = KK - 1; j >= 1; --j) {
            bool sh = v < kv[j - 1];
            bool he = v < kv[j];
            float pv = kv[j - 1]; int pi = ki[j - 1];
            kv[j] = sh ? pv : (he ? v : kv[j]);
            ki[j] = sh ? pi : (he ? m : ki[j]);
          }
          if (v < kv[0]) { kv[0] = v; ki[0] = m; }
        }
      }
    }
    cutq[orow * 4 + oq] = kv[KK - 1];  // benign race: values only tighten
  }

  // merge 4 quarter-lists per row -> per-half top-20 to global (keys+idx)
  __syncthreads();
  float* mv = Bs;                              // [r][q*20+k], stride 81 (5184 <= 8192)
  unsigned short* mi = (unsigned short*)As;    // u16, same indexing (2592 words <= 4096)
  #pragma unroll
  for (int k = 0; k < KK; ++k) {
    mv[orow * 81 + oq * 20 + k] = kv[k];
    mi[orow * 81 + oq * 20 + k] = (unsigned short)ki[k];
  }
  __syncthreads();
  if (t < 64) {
    int h0 = 0, h1 = 0, h2 = 0, h3 = 0;
    int rb = t * 81;
    size_t base = ((size_t)(b * NN + gr0 + t) * 2 + half) * KK;
    for (int k = 0; k < KK; ++k) {
      float v0 = mv[rb + h0];
      float v1 = mv[rb + 20 + h1];
      float v2 = mv[rb + 40 + h2];
      float v3 = mv[rb + 60 + h3];
      float bvv = v0; int bq = 0, bh = h0;
      if (v1 < bvv) { bvv = v1; bq = 1; bh = h1; }
      if (v2 < bvv) { bvv = v2; bq = 2; bh = h2; }
      if (v3 < bvv) { bvv = v3; bq = 3; bh = h3; }
      keys2[base + k] = bvv;
      idx2[base + k] = mi[rb + bq * 20 + bh];
      if (bq == 0) h0++; else if (bq == 1) h1++; else if (bq == 2) h2++; else h3++;
    }
  }
}

__global__ __launch_bounds__(256) void k3_out(const float* __restrict__ y1,
    const float* __restrict__ y2, const float* __restrict__ keys2,
    const unsigned short* __restrict__ idx2,
    const float* __restrict__ gamma, const float* __restrict__ beta,
    const float* __restrict__ rmean, const float* __restrict__ rvar,
    float* __restrict__ out) {
  __shared__ int sidx[64 * KK];
  __shared__ float ot[64 * 65];  // [o][n], pad 65
  int t = threadIdx.x;
  int b = blockIdx.x >> 6;
  int gr0 = (blockIdx.x & 63) << 6;
  if (t < 64) {  // 2-way merge of column-half lists -> final top-20 set
    size_t base0 = ((size_t)(b * NN + gr0 + t) * 2) * KK;
    size_t base1 = base0 + KK;
    int h0 = 0, h1 = 0;
    for (int k = 0; k < KK; ++k) {
      float v0 = keys2[base0 + (h0 < KK ? h0 : KK - 1)];
      float v1 = keys2[base1 + (h1 < KK ? h1 : KK - 1)];
      bool take0 = (h1 >= KK) || (h0 < KK && v0 <= v1);
      sidx[t * KK + k] = take0 ? (int)idx2[base0 + h0] : (int)idx2[base1 + h1];
      if (take0) h0++; else h1++;
    }
  }
  int l = t & 63, w = t >> 6;
  float sc = gamma[l] * rsqrtf(rvar[l] + EPSV);
  float tt = fmaf(-rmean[l], sc, beta[l]);
  __syncthreads();
  const float* y2b = y2 + (size_t)b * NN * NO;
  for (int rr = 0; rr < 16; ++rr) {
    int row = w * 16 + rr;
    float v1 = y1[((size_t)b * NN + gr0 + row) * NO + l];
    float best = -3.4e38f;
    #pragma unroll 4
    for (int k = 0; k < KK; ++k) {
      int m = sidx[row * KK + k];                 // wave-uniform broadcast
      float v = v1 + y2b[(size_t)m * NO + l];     // coalesced 256B gather
      v = fmaf(v, sc, tt);
      v = v >= 0.f ? v : SLOPE * v;
      best = fmaxf(best, v);
    }
    ot[l * 65 + row] = best;
  }
  __syncthreads();
  float* ob = out + (size_t)b * NO * NN;
  for (int i = t; i < 4096; i += 256) {
    int o = i >> 6, n = i & 63;
    ob[(size_t)o * NN + gr0 + n] = ot[o * 65 + n];  // coalesced
  }
}

extern "C" void kernel_launch(void* const* d_in, const int* in_sizes, int n_in,
                              void* d_out, int out_size, void* d_ws, size_t ws_size,
                              hipStream_t stream) {
  const float* x     = (const float*)d_in[0];
  const float* W     = (const float*)d_in[1];
  const float* gamma = (const float*)d_in[2];
  const float* beta  = (const float*)d_in[3];
  const float* rmean = (const float*)d_in[4];
  const float* rvar  = (const float*)d_in[5];
  float* ws  = (float*)d_ws;
  float* y1    = ws;
  float* y2    = ws + 2097152;
  float* xx    = ws + 4194304;
  float* keys2 = ws + 4227072;
  unsigned short* idx2 = (unsigned short*)(ws + 5537792);
  float* wa    = ws + 6193152;
  float* wb    = ws + 6197248;
  float* out = (float*)d_out;

  hipLaunchKernelGGL(k0_wprep, dim3(1),    dim3(256), 0, stream, W, wa, wb);
  hipLaunchKernelGGL(k1_feat,  dim3(512),  dim3(256), 0, stream, x, wa, wb, y1, y2, xx);
  hipLaunchKernelGGL(k2_topk,  dim3(1024), dim3(256), 0, stream, x, xx, keys2, idx2);
  hipLaunchKernelGGL(k3_out,   dim3(512),  dim3(256), 0, stream, y1, y2, keys2, idx2,
                     gamma, beta, rmean, rvar, out);
}

// Round 6
// 537.192 us; speedup vs baseline: 7.0203x; 1.2720x over previous
//
#include <hip/hip_runtime.h>

#define NB 8
#define NC 64
#define NN 4096
#define NO 64
#define KK 20
#define EPSV 1e-5f
#define SLOPE 0.2f

// ws layout (float words):
// y1   : [B][N][O]          @0         2097152
// y2   : [B][N][O]          @2097152   2097152
// xx   : [B][N]             @4194304   32768
// keyu : [B][N][2][20] u32  @4227072   1310720
// idxu : [B][N][2][20] u16  @5537792   655360 words
// wa   : [C][O]             @6193152   4096
// wb   : [C][O]             @6197248   4096

__global__ void k0_wprep(const float* __restrict__ W,
                         float* __restrict__ wa, float* __restrict__ wb) {
  int t = threadIdx.x;
  for (int i = t; i < NC * NO; i += 256) {
    int o = i & 63, c = i >> 6;
    float w1 = W[o * 128 + c];
    float w2 = W[o * 128 + 64 + c];
    wa[i] = w1 - w2;  // [c][o]
    wb[i] = w2;
  }
}

__global__ __launch_bounds__(256) void k1_feat(const float* __restrict__ x,
    const float* __restrict__ waT, const float* __restrict__ wbT,
    float* __restrict__ y1, float* __restrict__ y2, float* __restrict__ xxg) {
  __shared__ __align__(16) float xs[NC * 64];   // [c][n]
  __shared__ __align__(16) float wa[NC * NO];   // [c][o]
  __shared__ __align__(16) float wb[NC * NO];
  int t = threadIdx.x;
  int b = blockIdx.x >> 6;
  int gr0 = (blockIdx.x & 63) << 6;
  const float* xb = x + (size_t)b * NC * NN;
  #pragma unroll
  for (int k = 0; k < 4; ++k) {
    int i4 = t + k * 256;
    int c = i4 >> 4, col4 = (i4 & 15) << 2;
    *(float4*)&xs[c * 64 + col4] = *(const float4*)&xb[(size_t)c * NN + gr0 + col4];
    *(float4*)&wa[c * 64 + col4] = *(const float4*)&waT[c * 64 + col4];
    *(float4*)&wb[c * 64 + col4] = *(const float4*)&wbT[c * 64 + col4];
  }
  __syncthreads();
  if (t < 64) {
    float s = 0.f;
    #pragma unroll
    for (int c = 0; c < NC; ++c) { float v = xs[c * 64 + t]; s = fmaf(v, v, s); }
    xxg[b * NN + gr0 + t] = s;
  }
  int o = t & 63, w = t >> 6;
  for (int j = 0; j < 16; ++j) {
    int n = j * 4 + w;
    float a1 = 0.f, a2 = 0.f;
    #pragma unroll
    for (int c = 0; c < NC; ++c) {
      float xv = xs[c * 64 + n];               // wave-uniform broadcast
      a1 = fmaf(wa[c * 64 + o], xv, a1);
      a2 = fmaf(wb[c * 64 + o], xv, a2);
    }
    size_t base = ((size_t)b * NN + gr0 + n) * NO + o;
    y1[base] = a1;
    y2[base] = a2;
  }
}

__device__ __forceinline__ unsigned flipf(float f) {
  unsigned u = __float_as_uint(f);
  return u ^ ((unsigned)((int)u >> 31) | 0x80000000u);
}

// ----- fused Gram + per-row exact top-K (column half), mask+ctz scan -----
// grid 1024: blk = b*128 + rowgroup*2 + half
__global__ __launch_bounds__(256) void k2_topk(const float* __restrict__ x,
    const float* __restrict__ xxg, unsigned* __restrict__ keyuG,
    unsigned short* __restrict__ idxG) {
  __shared__ __align__(16) float smem[12288];   // As[4096]+Bs[8192]; merge reuse
  __shared__ __align__(16) float xxs[128];
  __shared__ unsigned cutq[256];                // [r][q], flipped-u32 domain
  float* As = smem;                             // [c][r]
  float* Bs = smem + 4096;                      // [c][m]; per-tile reused as candU
  unsigned* candU = (unsigned*)(smem + 4096);

  int t = threadIdx.x;
  int blk = blockIdx.x;
  int b = blk >> 7;
  int rem = blk & 127;
  int rg = rem >> 1, half = rem & 1;
  int gr0 = rg << 6;
  int gc0 = half << 11;                         // 0 or 2048
  const float* xb = x + (size_t)b * NC * NN;
  int ty = t >> 4, tx = t & 15;                 // rows ty*4..+3; cols {tx*4..+3}U{64+tx*4..+3}
  int orow = t & 63, oq = t >> 6;               // owner (row, quarter)

  #pragma unroll
  for (int k = 0; k < 4; ++k) {
    int i4 = t + k * 256;
    int c = i4 >> 4, col4 = (i4 & 15) << 2;
    *(float4*)&As[c * 64 + col4] = *(const float4*)&xb[(size_t)c * NN + gr0 + col4];
  }
  cutq[t] = 0xFFFFFFFFu;
  __syncthreads();

  unsigned long long lst[KK];                   // packed (flip(key)<<12)|m, ascending
  #pragma unroll
  for (int j = 0; j < KK; ++j) lst[j] = ~0ull;

  int rotw = (ty & 7) << 2;
  int rotr = ((orow >> 2) & 7) << 2;

  for (int mt = 0; mt < 16; ++mt) {
    int gm0 = gc0 + (mt << 7);
    __syncthreads();  // (a) prev cand reads done before Bs restage
    #pragma unroll
    for (int k = 0; k < 8; ++k) {
      int i4 = t + k * 256;
      int c = i4 >> 5, col4 = (i4 & 31) << 2;
      *(float4*)&Bs[c * 128 + col4] = *(const float4*)&xb[(size_t)c * NN + gm0 + col4];
    }
    if (t < 32) *(float4*)&xxs[t * 4] = *(const float4*)&xxg[b * NN + gm0 + t * 4];
    __syncthreads();  // (b) Bs ready

    float acc[4][8];
    #pragma unroll
    for (int i = 0; i < 4; ++i)
      #pragma unroll
      for (int j = 0; j < 8; ++j) acc[i][j] = 0.f;

    #pragma unroll 4
    for (int c = 0; c < 64; ++c) {
      float4 av = *(const float4*)&As[c * 64 + ty * 4];
      float4 b0 = *(const float4*)&Bs[c * 128 + tx * 4];        // 2-way max
      float4 b1 = *(const float4*)&Bs[c * 128 + 64 + tx * 4];
      float a_[4] = {av.x, av.y, av.z, av.w};
      float b_[8] = {b0.x, b0.y, b0.z, b0.w, b1.x, b1.y, b1.z, b1.w};
      #pragma unroll
      for (int i = 0; i < 4; ++i)
        #pragma unroll
        for (int j = 0; j < 8; ++j)
          acc[i][j] = fmaf(a_[i], b_[j], acc[i][j]);
    }

    // keys: xx[m] - 2*G (row-constant dropped; ordering identical)
    float xm[8];
    #pragma unroll
    for (int j = 0; j < 4; ++j) { xm[j] = xxs[tx * 4 + j]; xm[4 + j] = xxs[64 + tx * 4 + j]; }
    #pragma unroll
    for (int i = 0; i < 4; ++i)
      #pragma unroll
      for (int j = 0; j < 8; ++j)
        acc[i][j] = fmaf(-2.f, acc[i][j], xm[j]);

    __syncthreads();  // (c) Bs reads done -> safe to overwrite as candU

    // store flipped-u32 keys, swizzled cand[r][m]
    #pragma unroll
    for (int i = 0; i < 4; ++i) {
      int r = ty * 4 + i;
      #pragma unroll
      for (int h = 0; h < 2; ++h) {
        int mbw = h * 64 + tx * 4;
        int pos = (mbw & 96) | ((mbw + rotw) & 31);
        uint4 w;
        w.x = flipf(acc[i][h * 4 + 0]);
        w.y = flipf(acc[i][h * 4 + 1]);
        w.z = flipf(acc[i][h * 4 + 2]);
        w.w = flipf(acc[i][h * 4 + 3]);
        *(uint4*)&candU[r * 128 + pos] = w;
      }
    }
    __syncthreads();  // (d) cand ready

    // owner scan: branchless mask build, then ctz-compacted inserts
    unsigned rc0 = cutq[orow * 4 + 0], rc1 = cutq[orow * 4 + 1];
    unsigned rc2 = cutq[orow * 4 + 2], rc3 = cutq[orow * 4 + 3];
    unsigned thr = min(min(rc0, rc1), min(rc2, rc3));
    unsigned own19 = (unsigned)(lst[KK - 1] >> 12);
    thr = min(thr, own19);
    unsigned mask = 0;
    #pragma unroll
    for (int g = 0; g < 8; ++g) {
      int mb = oq * 32 + g * 4;
      int pos = (mb & 96) | ((mb + rotr) & 31);
      uint4 kw = *(const uint4*)&candU[orow * 128 + pos];
      mask |= (unsigned)(kw.x <= thr) << (g * 4 + 0);
      mask |= (unsigned)(kw.y <= thr) << (g * 4 + 1);
      mask |= (unsigned)(kw.z <= thr) << (g * 4 + 2);
      mask |= (unsigned)(kw.w <= thr) << (g * 4 + 3);
    }
    while (mask) {
      int e = __builtin_ctz(mask);
      mask &= mask - 1;
      int mb = oq * 32 + e;
      int pos = (mb & 96) | ((mb + rotr) & 31);
      unsigned ku = candU[orow * 128 + pos];
      unsigned long long p = ((unsigned long long)ku << 12) | (unsigned)(gm0 + mb);
      if (p < lst[KK - 1]) {
        #pragma unroll
        for (int j = KK - 1; j >= 1; --j) {
          bool sh = p < lst[j - 1];
          unsigned long long cur = (p < lst[j]) ? p : lst[j];
          lst[j] = sh ? lst[j - 1] : cur;
        }
        if (p < lst[0]) lst[0] = p;
      }
    }
    cutq[orow * 4 + oq] = (unsigned)(lst[KK - 1] >> 12);  // benign monotone race
  }

  // merge 4 quarter lists per row -> per-half top-20 to global
  __syncthreads();
  unsigned long long* M = (unsigned long long*)smem;  // [r][q*21+k], 5376 u64 <= 12288 f32
  #pragma unroll
  for (int k = 0; k < KK; ++k) M[orow * 84 + oq * 21 + k] = lst[k];
  M[orow * 84 + oq * 21 + KK] = ~0ull;                // sentinel
  __syncthreads();
  if (t < 64) {
    int h0 = 0, h1 = 0, h2 = 0, h3 = 0;
    int rb = t * 84;
    size_t base = ((size_t)(b * NN + gr0 + t) * 2 + half) * KK;
    for (int k = 0; k < KK; ++k) {
      unsigned long long v0 = M[rb + h0];
      unsigned long long v1 = M[rb + 21 + h1];
      unsigned long long v2 = M[rb + 42 + h2];
      unsigned long long v3 = M[rb + 63 + h3];
      unsigned long long bv = v0; int bq = 0;
      if (v1 < bv) { bv = v1; bq = 1; }
      if (v2 < bv) { bv = v2; bq = 2; }
      if (v3 < bv) { bv = v3; bq = 3; }
      keyuG[base + k] = (unsigned)(bv >> 12);
      idxG[base + k] = (unsigned short)(bv & 0xFFFu);
      if (bq == 0) h0++; else if (bq == 1) h1++; else if (bq == 2) h2++; else h3++;
    }
  }
}

__global__ __launch_bounds__(256) void k3_out(const float* __restrict__ y1,
    const float* __restrict__ y2, const unsigned* __restrict__ keyuG,
    const unsigned short* __restrict__ idxG,
    const float* __restrict__ gamma, const float* __restrict__ beta,
    const float* __restrict__ rmean, const float* __restrict__ rvar,
    float* __restrict__ out) {
  __shared__ int sidx[64 * KK];
  __shared__ float ot[64 * 65];  // [o][n], pad 65
  int t = threadIdx.x;
  int b = blockIdx.x >> 6;
  int gr0 = (blockIdx.x & 63) << 6;
  if (t < 64) {  // 2-way merge of column-half lists (lex by flipped key, then idx)
    size_t base0 = ((size_t)(b * NN + gr0 + t) * 2) * KK;
    size_t base1 = base0 + KK;
    int h0 = 0, h1 = 0;
    for (int k = 0; k < KK; ++k) {
      int a0 = h0 < KK ? h0 : KK - 1;
      int a1 = h1 < KK ? h1 : KK - 1;
      unsigned k0v = keyuG[base0 + a0]; unsigned i0 = idxG[base0 + a0];
      unsigned k1v = keyuG[base1 + a1]; unsigned i1 = idxG[base1 + a1];
      bool take0 = (h1 >= KK) ||
                   ((h0 < KK) && (k0v < k1v || (k0v == k1v && i0 < i1)));
      sidx[t * KK + k] = take0 ? (int)i0 : (int)i1;
      if (take0) h0++; else h1++;
    }
  }
  int l = t & 63, w = t >> 6;
  float sc = gamma[l] * rsqrtf(rvar[l] + EPSV);
  float tt = fmaf(-rmean[l], sc, beta[l]);
  __syncthreads();
  const float* y2b = y2 + (size_t)b * NN * NO;
  for (int rr = 0; rr < 16; ++rr) {
    int row = w * 16 + rr;
    float v1 = y1[((size_t)b * NN + gr0 + row) * NO + l];
    float best = -3.4e38f;
    #pragma unroll 4
    for (int k = 0; k < KK; ++k) {
      int m = sidx[row * KK + k];                 // wave-uniform broadcast
      float v = v1 + y2b[(size_t)m * NO + l];     // coalesced 256B gather
      v = fmaf(v, sc, tt);
      v = v >= 0.f ? v : SLOPE * v;
      best = fmaxf(best, v);
    }
    ot[l * 65 + row] = best;
  }
  __syncthreads();
  float* ob = out + (size_t)b * NO * NN;
  for (int i = t; i < 4096; i += 256) {
    int o = i >> 6, n = i & 63;
    ob[(size_t)o * NN + gr0 + n] = ot[o * 65 + n];  // coalesced
  }
}

extern "C" void kernel_launch(void* const* d_in, const int* in_sizes, int n_in,
                              void* d_out, int out_size, void* d_ws, size_t ws_size,
                              hipStream_t stream) {
  const float* x     = (const float*)d_in[0];
  const float* W     = (const float*)d_in[1];
  const float* gamma = (const float*)d_in[2];
  const float* beta  = (const float*)d_in[3];
  const float* rmean = (const float*)d_in[4];
  const float* rvar  = (const float*)d_in[5];
  float* ws  = (float*)d_ws;
  float* y1    = ws;
  float* y2    = ws + 2097152;
  float* xx    = ws + 4194304;
  unsigned* keyu = (unsigned*)(ws + 4227072);
  unsigned short* idxu = (unsigned short*)(ws + 5537792);
  float* wa    = ws + 6193152;
  float* wb    = ws + 6197248;
  float* out = (float*)d_out;

  hipLaunchKernelGGL(k0_wprep, dim3(1),    dim3(256), 0, stream, W, wa, wb);
  hipLaunchKernelGGL(k1_feat,  dim3(512),  dim3(256), 0, stream, x, wa, wb, y1, y2, xx);
  hipLaunchKernelGGL(k2_topk,  dim3(1024), dim3(256), 0, stream, x, xx, keyu, idxu);
  hipLaunchKernelGGL(k3_out,   dim3(512),  dim3(256), 0, stream, y1, y2, keyu, idxu,
                     gamma, beta, rmean, rvar, out);
}

// Round 7
// 460.636 us; speedup vs baseline: 8.1870x; 1.1662x over previous
//
#include <hip/hip_runtime.h>

#define NB 8
#define NC 64
#define NN 4096
#define NO 64
#define KK 20
#define EPSV 1e-5f
#define SLOPE 0.2f

typedef __attribute__((ext_vector_type(8))) short short8x;
typedef __attribute__((ext_vector_type(4))) float float4x;

// ws layout (float words):
// y1   : [B][N][O]            @0         2097152
// y2   : [B][N][O]            @2097152   2097152
// xx   : [B][N]               @4194304   32768
// keyu : [B][N][2][20] u32    @4227072   1310720
// idxu : [B][N][2][20] u16    @5537792   655360 words
// wa   : [C][O]               @6193152   4096
// wb   : [C][O]               @6197248   4096
// xThi : [B][N][C] bf16       @6201344   1048576
// xTmid: [B][N][C] bf16       @7249920   1048576
// xTlo : [B][N][C] bf16       @8298496   1048576
// total 9347072 words = 37.4 MB

__device__ __forceinline__ unsigned short bfh(float f) {  // fp32 -> bf16 (RNE)
  unsigned u = __float_as_uint(f);
  unsigned r = u + 0x7FFFu + ((u >> 16) & 1u);
  return (unsigned short)(r >> 16);
}

__device__ __forceinline__ unsigned flipf(float f) {
  unsigned u = __float_as_uint(f);
  return u ^ ((unsigned)((int)u >> 31) | 0x80000000u);
}

__global__ void k0_wprep(const float* __restrict__ W,
                         float* __restrict__ wa, float* __restrict__ wb) {
  int t = threadIdx.x;
  for (int i = t; i < NC * NO; i += 256) {
    int o = i & 63, c = i >> 6;
    float w1 = W[o * 128 + c];
    float w2 = W[o * 128 + 64 + c];
    wa[i] = w1 - w2;  // [c][o]
    wb[i] = w2;
  }
}

__global__ __launch_bounds__(256) void k1_feat(const float* __restrict__ x,
    const float* __restrict__ waT, const float* __restrict__ wbT,
    float* __restrict__ y1, float* __restrict__ y2, float* __restrict__ xxg,
    unsigned short* __restrict__ xThi, unsigned short* __restrict__ xTmid,
    unsigned short* __restrict__ xTlo) {
  __shared__ __align__(16) float xs[NC * 68];   // [c][n] stride 68 (transpose-read banks)
  __shared__ __align__(16) float wa[NC * NO];
  __shared__ __align__(16) float wb[NC * NO];
  int t = threadIdx.x;
  int b = blockIdx.x >> 6;
  int gr0 = (blockIdx.x & 63) << 6;
  const float* xb = x + (size_t)b * NC * NN;
  #pragma unroll
  for (int k = 0; k < 4; ++k) {
    int i4 = t + k * 256;
    int c = i4 >> 4, col4 = (i4 & 15) << 2;
    *(float4*)&xs[c * 68 + col4] = *(const float4*)&xb[(size_t)c * NN + gr0 + col4];
    *(float4*)&wa[c * 64 + col4] = *(const float4*)&waT[c * 64 + col4];
    *(float4*)&wb[c * 64 + col4] = *(const float4*)&wbT[c * 64 + col4];
  }
  __syncthreads();
  if (t < 64) {
    float s = 0.f;
    #pragma unroll
    for (int c = 0; c < NC; ++c) { float v = xs[c * 68 + t]; s = fmaf(v, v, s); }
    xxg[b * NN + gr0 + t] = s;
  }
  int o = t & 63, w = t >> 6;
  for (int j = 0; j < 16; ++j) {
    int n = j * 4 + w;
    float a1 = 0.f, a2 = 0.f;
    #pragma unroll
    for (int c = 0; c < NC; ++c) {
      float xv = xs[c * 68 + n];               // wave-uniform broadcast
      a1 = fmaf(wa[c * 64 + o], xv, a1);
      a2 = fmaf(wb[c * 64 + o], xv, a2);
    }
    size_t base = ((size_t)b * NN + gr0 + n) * NO + o;
    y1[base] = a1;
    y2[base] = a2;
  }
  // 3-way bf16 split, transposed layout xT[b][n][c]
  int n2 = t >> 2, c0 = (t & 3) << 4;
  short8x vh[2], vm[2], vl[2];
  #pragma unroll
  for (int i = 0; i < 16; ++i) {
    float v = xs[(c0 + i) * 68 + n2];
    unsigned short h = bfh(v);
    float hf = __uint_as_float((unsigned)h << 16);
    float r1 = v - hf;
    unsigned short md = bfh(r1);
    float mf = __uint_as_float((unsigned)md << 16);
    unsigned short lo = bfh(r1 - mf);
    vh[i >> 3][i & 7] = (short)h;
    vm[i >> 3][i & 7] = (short)md;
    vl[i >> 3][i & 7] = (short)lo;
  }
  size_t tb = ((size_t)(b * NN + gr0 + n2)) * 64 + c0;
  *(short8x*)&xThi[tb] = vh[0];  *(short8x*)&xThi[tb + 8] = vh[1];
  *(short8x*)&xTmid[tb] = vm[0]; *(short8x*)&xTmid[tb + 8] = vm[1];
  *(short8x*)&xTlo[tb] = vl[0];  *(short8x*)&xTlo[tb + 8] = vl[1];
}

// ----- MFMA split-bf16 Gram + per-row exact top-K (column half) -----
// grid 1024: blk = b*128 + rowgroup*2 + half
__global__ __launch_bounds__(256, 3) void k2_topk(
    const unsigned short* __restrict__ xThi, const unsigned short* __restrict__ xTmid,
    const unsigned short* __restrict__ xTlo, const float* __restrict__ xxg,
    unsigned* __restrict__ keyuG, unsigned short* __restrict__ idxG) {
  __shared__ __align__(16) unsigned short Rb[3 * 8192];  // 48KB: B-tiles hi/mid/lo
                                                         // alias: candU u32[8192]; M u64[5376]
  __shared__ __align__(16) float xxs[128];
  __shared__ unsigned cutq[256];                          // [r][q], flipped-u32 domain
  unsigned* candU = (unsigned*)Rb;

  int t = threadIdx.x;
  int blk = blockIdx.x;
  int b = blk >> 7;
  int rem = blk & 127;
  int rg = rem >> 1, half = rem & 1;
  int gr0 = rg << 6;
  int gc0 = half << 11;                         // 0 or 2048
  int w = t >> 6;                               // wave: rows 16w..16w+15
  int lm = t & 15;                              // lane&15: A-row / B-col / D-col
  int quad = (t >> 4) & 3;                      // lane>>4: k-octet / D-row-quad
  int orow = t & 63, oq = t >> 6;               // owner (row, quarter)

  // persistent A-fragments from global (rows gr0+16w+lm, 3 levels x 2 k-steps)
  size_t abase = ((size_t)(b * NN + gr0 + 16 * w + lm)) * 64;
  short8x Ah[2], Am[2], Al[2];
  #pragma unroll
  for (int ks = 0; ks < 2; ++ks) {
    int co = ks * 32 + quad * 8;
    Ah[ks] = *(const short8x*)&xThi[abase + co];
    Am[ks] = *(const short8x*)&xTmid[abase + co];
    Al[ks] = *(const short8x*)&xTlo[abase + co];
  }
  cutq[t] = 0xFFFFFFFFu;

  unsigned long long lst[KK];                   // packed (flip(key)<<12)|m, ascending
  #pragma unroll
  for (int j = 0; j < KK; ++j) lst[j] = ~0ull;

  int rotr = (orow & 7) << 2;                   // reader swizzle (matches writer r&7)
  size_t bbase = (size_t)(b * NN) * 64;

  for (int mt = 0; mt < 16; ++mt) {
    int gm0 = gc0 + (mt << 7);
    __syncthreads();  // (a) prev cand consumed; safe to restage Rb
    // stage B-tile: 3 levels x 128 pts x 64 c, octet-rotated
    #pragma unroll
    for (int lvl = 0; lvl < 3; ++lvl) {
      const unsigned short* src = (lvl == 0) ? xThi : (lvl == 1) ? xTmid : xTlo;
      unsigned short* dst = Rb + lvl * 8192;
      #pragma unroll
      for (int p = 0; p < 4; ++p) {
        int idx = p * 256 + t;
        int n = idx >> 3, o = idx & 7;
        *(short8x*)&dst[n * 64 + ((o + n) & 7) * 8] =
            *(const short8x*)&src[bbase + (size_t)(gm0 + n) * 64 + o * 8];
      }
    }
    if (t < 32) *(float4*)&xxs[t * 4] = *(const float4*)&xxg[b * NN + gm0 + t * 4];
    __syncthreads();  // (b) Rb ready

    float4x acc[8];
    #pragma unroll
    for (int j = 0; j < 8; ++j) acc[j] = (float4x){0.f, 0.f, 0.f, 0.f};

    const unsigned short* RbH = Rb;
    const unsigned short* RbM = Rb + 8192;
    const unsigned short* RbL = Rb + 16384;
    #pragma unroll
    for (int ks = 0; ks < 2; ++ks) {
      #pragma unroll
      for (int j = 0; j < 8; ++j) {
        int n = 16 * j + lm;
        int off = n * 64 + ((ks * 4 + quad + n) & 7) * 8;
        short8x bh = *(const short8x*)&RbH[off];
        short8x bm = *(const short8x*)&RbM[off];
        short8x bl = *(const short8x*)&RbL[off];
        acc[j] = __builtin_amdgcn_mfma_f32_16x16x32_bf16(Am[ks], bm, acc[j], 0, 0, 0);
        acc[j] = __builtin_amdgcn_mfma_f32_16x16x32_bf16(Ah[ks], bl, acc[j], 0, 0, 0);
        acc[j] = __builtin_amdgcn_mfma_f32_16x16x32_bf16(Al[ks], bh, acc[j], 0, 0, 0);
        acc[j] = __builtin_amdgcn_mfma_f32_16x16x32_bf16(Ah[ks], bm, acc[j], 0, 0, 0);
        acc[j] = __builtin_amdgcn_mfma_f32_16x16x32_bf16(Am[ks], bh, acc[j], 0, 0, 0);
        acc[j] = __builtin_amdgcn_mfma_f32_16x16x32_bf16(Ah[ks], bh, acc[j], 0, 0, 0);
      }
    }

    float xq[8];
    #pragma unroll
    for (int j = 0; j < 8; ++j) xq[j] = xxs[16 * j + lm];

    __syncthreads();  // (c) all Rb reads done -> overwrite as candU

    // keys: xx[m] - 2*G (row-constant dropped); D layout: col=lm+16j, row=quad*4+q
    #pragma unroll
    for (int j = 0; j < 8; ++j) {
      int c = 16 * j + lm;
      #pragma unroll
      for (int q = 0; q < 4; ++q) {
        int rl = quad * 4 + q;
        int r = 16 * w + rl;
        float key = fmaf(-2.f, acc[j][q], xq[j]);
        int pos = (c & 96) | ((c + ((rl & 7) << 2)) & 31);
        candU[r * 128 + pos] = flipf(key);
      }
    }
    __syncthreads();  // (d) cand ready

    // owner scan: branchless mask build, then ctz-compacted inserts
    unsigned rc0 = cutq[orow * 4 + 0], rc1 = cutq[orow * 4 + 1];
    unsigned rc2 = cutq[orow * 4 + 2], rc3 = cutq[orow * 4 + 3];
    unsigned thr = min(min(rc0, rc1), min(rc2, rc3));
    unsigned own19 = (unsigned)(lst[KK - 1] >> 12);
    thr = min(thr, own19);
    unsigned mask = 0;
    #pragma unroll
    for (int g = 0; g < 8; ++g) {
      int mb = oq * 32 + g * 4;
      int pos = (mb & 96) | ((mb + rotr) & 31);
      uint4 kw = *(const uint4*)&candU[orow * 128 + pos];
      mask |= (unsigned)(kw.x <= thr) << (g * 4 + 0);
      mask |= (unsigned)(kw.y <= thr) << (g * 4 + 1);
      mask |= (unsigned)(kw.z <= thr) << (g * 4 + 2);
      mask |= (unsigned)(kw.w <= thr) << (g * 4 + 3);
    }
    while (mask) {
      int e = __builtin_ctz(mask);
      mask &= mask - 1;
      int mb = oq * 32 + e;
      int pos = (mb & 96) | ((mb + rotr) & 31);
      unsigned ku = candU[orow * 128 + pos];
      unsigned long long p = ((unsigned long long)ku << 12) | (unsigned)(gm0 + mb);
      if (p < lst[KK - 1]) {
        #pragma unroll
        for (int j = KK - 1; j >= 1; --j) {
          bool sh = p < lst[j - 1];
          unsigned long long cur = (p < lst[j]) ? p : lst[j];
          lst[j] = sh ? lst[j - 1] : cur;
        }
        if (p < lst[0]) lst[0] = p;
      }
    }
    cutq[orow * 4 + oq] = (unsigned)(lst[KK - 1] >> 12);  // benign monotone race
  }

  // merge 4 quarter lists per row -> per-half top-20 to global
  __syncthreads();
  unsigned long long* M = (unsigned long long*)Rb;  // [r][q*21+k], 5376 u64 = 43KB <= 48KB
  #pragma unroll
  for (int k = 0; k < KK; ++k) M[orow * 84 + oq * 21 + k] = lst[k];
  M[orow * 84 + oq * 21 + KK] = ~0ull;              // sentinel
  __syncthreads();
  if (t < 64) {
    int h0 = 0, h1 = 0, h2 = 0, h3 = 0;
    int rb = t * 84;
    size_t base = ((size_t)(b * NN + gr0 + t) * 2 + half) * KK;
    for (int k = 0; k < KK; ++k) {
      unsigned long long v0 = M[rb + h0];
      unsigned long long v1 = M[rb + 21 + h1];
      unsigned long long v2 = M[rb + 42 + h2];
      unsigned long long v3 = M[rb + 63 + h3];
      unsigned long long bv = v0; int bq = 0;
      if (v1 < bv) { bv = v1; bq = 1; }
      if (v2 < bv) { bv = v2; bq = 2; }
      if (v3 < bv) { bv = v3; bq = 3; }
      keyuG[base + k] = (unsigned)(bv >> 12);
      idxG[base + k] = (unsigned short)(bv & 0xFFFu);
      if (bq == 0) h0++; else if (bq == 1) h1++; else if (bq == 2) h2++; else h3++;
    }
  }
}

__global__ __launch_bounds__(256) void k3_out(const float* __restrict__ y1,
    const float* __restrict__ y2, const unsigned* __restrict__ keyuG,
    const unsigned short* __restrict__ idxG,
    const float* __restrict__ gamma, const float* __restrict__ beta,
    const float* __restrict__ rmean, const float* __restrict__ rvar,
    float* __restrict__ out) {
  __shared__ int sidx[64 * KK];
  __shared__ float ot[64 * 65];  // [o][n], pad 65
  int t = threadIdx.x;
  int b = blockIdx.x >> 6;
  int gr0 = (blockIdx.x & 63) << 6;
  if (t < 64) {  // 2-way merge of column-half lists (lex by flipped key, then idx)
    size_t base0 = ((size_t)(b * NN + gr0 + t) * 2) * KK;
    size_t base1 = base0 + KK;
    int h0 = 0, h1 = 0;
    for (int k = 0; k < KK; ++k) {
      int a0 = h0 < KK ? h0 : KK - 1;
      int a1 = h1 < KK ? h1 : KK - 1;
      unsigned k0v = keyuG[base0 + a0]; unsigned i0 = idxG[base0 + a0];
      unsigned k1v = keyuG[base1 + a1]; unsigned i1 = idxG[base1 + a1];
      bool take0 = (h1 >= KK) ||
                   ((h0 < KK) && (k0v < k1v || (k0v == k1v && i0 < i1)));
      sidx[t * KK + k] = take0 ? (int)i0 : (int)i1;
      if (take0) h0++; else h1++;
    }
  }
  int l = t & 63, w = t >> 6;
  float sc = gamma[l] * rsqrtf(rvar[l] + EPSV);
  float tt = fmaf(-rmean[l], sc, beta[l]);
  __syncthreads();
  const float* y2b = y2 + (size_t)b * NN * NO;
  for (int rr = 0; rr < 16; ++rr) {
    int row = w * 16 + rr;
    float v1 = y1[((size_t)b * NN + gr0 + row) * NO + l];
    float best = -3.4e38f;
    #pragma unroll 4
    for (int k = 0; k < KK; ++k) {
      int m = sidx[row * KK + k];                 // wave-uniform broadcast
      float v = v1 + y2b[(size_t)m * NO + l];     // coalesced 256B gather
      v = fmaf(v, sc, tt);
      v = v >= 0.f ? v : SLOPE * v;
      best = fmaxf(best, v);
    }
    ot[l * 65 + row] = best;
  }
  __syncthreads();
  float* ob = out + (size_t)b * NO * NN;
  for (int i = t; i < 4096; i += 256) {
    int o = i >> 6, n = i & 63;
    ob[(size_t)o * NN + gr0 + n] = ot[o * 65 + n];  // coalesced
  }
}

extern "C" void kernel_launch(void* const* d_in, const int* in_sizes, int n_in,
                              void* d_out, int out_size, void* d_ws, size_t ws_size,
                              hipStream_t stream) {
  const float* x     = (const float*)d_in[0];
  const float* W     = (const float*)d_in[1];
  const float* gamma = (const float*)d_in[2];
  const float* beta  = (const float*)d_in[3];
  const float* rmean = (const float*)d_in[4];
  const float* rvar  = (const float*)d_in[5];
  float* ws  = (float*)d_ws;
  float* y1    = ws;
  float* y2    = ws + 2097152;
  float* xx    = ws + 4194304;
  unsigned* keyu = (unsigned*)(ws + 4227072);
  unsigned short* idxu = (unsigned short*)(ws + 5537792);
  float* wa    = ws + 6193152;
  float* wb    = ws + 6197248;
  unsigned short* xThi  = (unsigned short*)(ws + 6201344);
  unsigned short* xTmid = (unsigned short*)(ws + 7249920);
  unsigned short* xTlo  = (unsigned short*)(ws + 8298496);
  float* out = (float*)d_out;

  hipLaunchKernelGGL(k0_wprep, dim3(1),    dim3(256), 0, stream, W, wa, wb);
  hipLaunchKernelGGL(k1_feat,  dim3(512),  dim3(256), 0, stream, x, wa, wb, y1, y2, xx,
                     xThi, xTmid, xTlo);
  hipLaunchKernelGGL(k2_topk,  dim3(1024), dim3(256), 0, stream, xThi, xTmid, xTlo,
                     xx, keyu, idxu);
  hipLaunchKernelGGL(k3_out,   dim3(512),  dim3(256), 0, stream, y1, y2, keyu, idxu,
                     gamma, beta, rmean, rvar, out);
}